// Round 1
// baseline (377.891 us; speedup 1.0000x reference)
//
#include <hip/hip_runtime.h>

#define LATENT 128
#define HIDDEN 256
#define OUTD   128
#define TT     100
#define DECH   64

typedef _Float16 f16x8 __attribute__((ext_vector_type(8)));
typedef float    f32x4 __attribute__((ext_vector_type(4)));

#define MFMA16(a,b,c) __builtin_amdgcn_mfma_f32_16x16x32_f16((a),(b),(c),0,0,0)

__device__ __forceinline__ float tanh_fast(float x){
    float e = __expf(2.f*x);                       // e^{2x}
    return 1.f - 2.f*__builtin_amdgcn_rcpf(e + 1.f); // 1 - 2/(e^{2x}+1); exact limits at +-inf
}

// XOR-swizzled LDS helpers (row-major tile, strideB bytes/row; swizzle keeps
// 16B granules, so 16B reads stay contiguous and ds_read_b128 is conflict-free)
__device__ __forceinline__ f16x8 lds_rd8(const _Float16* base, int strideB, int row, int colE){
    int off = row*strideB + colE*2;
    off ^= (row&7)<<4;
    return *(const f16x8*)((const char*)base + off);
}
__device__ __forceinline__ void lds_wr1(_Float16* base, int strideB, int row, int colE, float v){
    int off = row*strideB + colE*2;
    off ^= (row&7)<<4;
    *(_Float16*)((char*)base + off) = (_Float16)v;
}

// one-time gather of a stage-invariant B fragment from row-major fp32 W[K][N]
// lane layout: B[k0 + 8*(lane>>4) + i][n0 + (lane&15)]
__device__ __forceinline__ f16x8 gbl_bfrag(const float* W, int ldN, int k0, int n){
    f16x8 f;
#pragma unroll
    for(int i=0;i<8;++i) f[i] = (_Float16)W[(size_t)(k0+i)*ldN + n];
    return f;
}

__global__ __launch_bounds__(512, 2) void ode_decoder_kernel(
    const float* __restrict__ z0, const float* __restrict__ times,
    const float* __restrict__ W1, const float* __restrict__ b1,
    const float* __restrict__ W2, const float* __restrict__ b2,
    const float* __restrict__ dW1, const float* __restrict__ db1,
    const float* __restrict__ dW2, const float* __restrict__ db2,
    const float* __restrict__ dW3, const float* __restrict__ db3,
    float* __restrict__ out)
{
    __shared__ _Float16 z_lds [16*LATENT] __attribute__((aligned(16)));
    __shared__ _Float16 h_lds [16*HIDDEN] __attribute__((aligned(16)));
    __shared__ _Float16 h1_lds[16*DECH]   __attribute__((aligned(16)));
    __shared__ _Float16 h2_lds[16*DECH]   __attribute__((aligned(16)));

    const int tid   = threadIdx.x;
    const int wv    = tid >> 6;      // wave 0..7
    const int lane  = tid & 63;
    const int lr    = lane & 15;
    const int lg    = lane >> 4;     // 0..3
    const int row0  = lg*4;          // D-frag row base within 16-row tile
    const int gRow0 = blockIdx.x*16; // this WG's batch-row base

    // ---------- one-time: pin all B-operand fragments in VGPRs ----------
    // GEMM1: [16,128]@W1[128,256]; wave owns n in [32w,32w+32) as 2 n-tiles
    f16x8 w1f[2][4];
#pragma unroll
    for(int t=0;t<2;++t)
#pragma unroll
        for(int q=0;q<4;++q)
            w1f[t][q] = gbl_bfrag(W1, HIDDEN, 32*q+8*lg, 32*wv+16*t+lr);
    // GEMM2: [16,256]@W2[256,128]; wave owns n in [16w,16w+16)
    f16x8 w2f[8];
#pragma unroll
    for(int q=0;q<8;++q)
        w2f[q] = gbl_bfrag(W2, LATENT, 32*q+8*lg, 16*wv+lr);

    // decoder frags: dGEMM1/2 run on waves 0-3 only (N=64); dGEMM3 on all 8
    const int dcol = (wv<4) ? (16*wv+lr) : lr;   // clamp to stay in-bounds for idle waves
    f16x8 dw1f[4], dw2f[2], dw3f[2];
#pragma unroll
    for(int q=0;q<4;++q) dw1f[q] = gbl_bfrag(dW1, DECH, 32*q+8*lg, dcol);
#pragma unroll
    for(int q=0;q<2;++q) dw2f[q] = gbl_bfrag(dW2, DECH, 32*q+8*lg, dcol);
#pragma unroll
    for(int q=0;q<2;++q) dw3f[q] = gbl_bfrag(dW3, OUTD, 32*q+8*lg, 16*wv+lr);

    const float b1v0 = b1[32*wv+lr], b1v1 = b1[32*wv+16+lr];
    const float b2v  = b2[16*wv+lr];
    const float db1v = db1[dcol],    db2v = db2[dcol];
    const float db3v = db3[16*wv+lr];

    // ---------- state: lane owns z[row0+r][16*wv+lr], r=0..3 (D-frag layout) ----------
    f32x4 z;
#pragma unroll
    for(int r=0;r<4;++r) z[r] = z0[(size_t)(gRow0+row0+r)*LATENT + 16*wv + lr];
#pragma unroll
    for(int r=0;r<4;++r) lds_wr1(z_lds, LATENT*2, row0+r, 16*wv+lr, z[r]);
    __syncthreads();

    f32x4 acc = {0.f,0.f,0.f,0.f};
#pragma unroll 1
    for(int k=0;k<TT;++k){
        // ================= decode z(t_k) -> out[:, k, :] =================
        if(wv<4){                                   // dGEMM1: relu(z@dW1+db1) -> h1
            f16x8 a[4];
#pragma unroll
            for(int q=0;q<4;++q) a[q] = lds_rd8(z_lds, LATENT*2, lr, 32*q+8*lg);
            f32x4 c = {db1v,db1v,db1v,db1v};
#pragma unroll
            for(int q=0;q<4;++q) c = MFMA16(a[q], dw1f[q], c);
#pragma unroll
            for(int r=0;r<4;++r) lds_wr1(h1_lds, DECH*2, row0+r, 16*wv+lr, fmaxf(c[r],0.f));
        }
        __syncthreads();
        if(wv<4){                                   // dGEMM2: relu(h1@dW2+db2) -> h2
            f32x4 c = {db2v,db2v,db2v,db2v};
#pragma unroll
            for(int q=0;q<2;++q) c = MFMA16(lds_rd8(h1_lds, DECH*2, lr, 32*q+8*lg), dw2f[q], c);
#pragma unroll
            for(int r=0;r<4;++r) lds_wr1(h2_lds, DECH*2, row0+r, 16*wv+lr, fmaxf(c[r],0.f));
        }
        __syncthreads();
        {                                           // dGEMM3: h2@dW3+db3 -> out
            f32x4 c = {db3v,db3v,db3v,db3v};
#pragma unroll
            for(int q=0;q<2;++q) c = MFMA16(lds_rd8(h2_lds, DECH*2, lr, 32*q+8*lg), dw3f[q], c);
            float* op = out + (size_t)(gRow0+row0)*TT*OUTD + (size_t)k*OUTD + 16*wv + lr;
#pragma unroll
            for(int r=0;r<4;++r) op[(size_t)r*TT*OUTD] = c[r];
        }
        if(k==TT-1) break;

        const float hs = times[k+1]-times[k];
        // ================= RK4 over [t_k, t_{k+1}] =================
        // z_lds currently holds fp16(z); each stage: f(z_stage), then write next z_stage
#pragma unroll
        for(int s=0;s<4;++s){
            // GEMM1: C1 = Zs @ W1 + b1 ; H = tanh(C1)
            f16x8 a[4];
#pragma unroll
            for(int q=0;q<4;++q) a[q] = lds_rd8(z_lds, LATENT*2, lr, 32*q+8*lg);
            f32x4 c0 = {b1v0,b1v0,b1v0,b1v0};
            f32x4 c1 = {b1v1,b1v1,b1v1,b1v1};
#pragma unroll
            for(int q=0;q<4;++q){
                c0 = MFMA16(a[q], w1f[0][q], c0);
                c1 = MFMA16(a[q], w1f[1][q], c1);
            }
#pragma unroll
            for(int r=0;r<4;++r){
                lds_wr1(h_lds, HIDDEN*2, row0+r, 32*wv+lr,    tanh_fast(c0[r]));
                lds_wr1(h_lds, HIDDEN*2, row0+r, 32*wv+16+lr, tanh_fast(c1[r]));
            }
            __syncthreads();   // h ready; also: all z_lds reads for this stage done
            // GEMM2: kk = H @ W2 + b2
            f32x4 kk = {b2v,b2v,b2v,b2v};
#pragma unroll
            for(int q=0;q<8;++q)
                kk = MFMA16(lds_rd8(h_lds, HIDDEN*2, lr, 32*q+8*lg), w2f[q], kk);
            // RK4 combine (fp32 state in registers)
            f32x4 zs;
            if(s==0)      { acc = z + kk*(hs*(1.f/6.f)); zs = z + kk*(hs*0.5f); }
            else if(s==1) { acc += kk*(hs*(1.f/3.f));    zs = z + kk*(hs*0.5f); }
            else if(s==2) { acc += kk*(hs*(1.f/3.f));    zs = z + kk*hs; }
            else          { z = acc + kk*(hs*(1.f/6.f)); zs = z; }
#pragma unroll
            for(int r=0;r<4;++r) lds_wr1(z_lds, LATENT*2, row0+r, 16*wv+lr, zs[r]);
            __syncthreads();   // next stage (or decode) reads z_lds
        }
    }
}

extern "C" void kernel_launch(void* const* d_in, const int* in_sizes, int n_in,
                              void* d_out, int out_size, void* d_ws, size_t ws_size,
                              hipStream_t stream) {
    ode_decoder_kernel<<<dim3(256), dim3(512), 0, stream>>>(
        (const float*)d_in[0],  (const float*)d_in[1],
        (const float*)d_in[2],  (const float*)d_in[3],
        (const float*)d_in[4],  (const float*)d_in[5],
        (const float*)d_in[6],  (const float*)d_in[7],
        (const float*)d_in[8],  (const float*)d_in[9],
        (const float*)d_in[10], (const float*)d_in[11],
        (float*)d_out);
}